// Round 1
// baseline (1307.561 us; speedup 1.0000x reference)
//
#include <hip/hip_runtime.h>
#include <math.h>

#define TB  2
#define TT  2048
#define TC  768
#define TH  12
#define TDH 64
#define TI  3072
#define TM  (TB*TT)   // 4096 rows

// ---------------------------------------------------------------------------
// Tiled fp32 GEMM: out = A[M,K] @ W[K,N] (+ epilogue)
//   ep 0: QKV split-head store: out[((b*H+h)*T + t)*64 + d] = acc + bias  (grid.x == 12, h = blockIdx.x)
//   ep 1: out[m*N+n] = acc + bias[n] + resid[m*N+n]
//   ep 2: out[m*N+n] = gelu_tanh(acc + bias[n])
// Block: 256 threads (16x16), 64x64 tile, BK=16, 4x4 micro-tile per thread.
// ---------------------------------------------------------------------------
__device__ __forceinline__ float gelu_tanh(float x) {
    float x3 = x * x * x;
    return 0.5f * x * (1.0f + tanhf(0.7978845608028654f * (x + 0.044715f * x3)));
}

__global__ __launch_bounds__(256)
void gemm_ep(const float* __restrict__ A, const float* __restrict__ W,
             const float* __restrict__ bias, const float* __restrict__ resid,
             float* __restrict__ out, int M, int N, int K, int ep)
{
    __shared__ float As[16 * 64];   // [kk][m]
    __shared__ float Bs[16 * 64];   // [kk][n]
    const int tid = threadIdx.x;
    const int tx = tid & 15, ty = tid >> 4;
    const int m0 = blockIdx.y * 64, n0 = blockIdx.x * 64;

    const int ar  = tid >> 2;          // 0..63 : A tile row
    const int ac4 = (tid & 3) * 4;     // 0,4,8,12 : A tile col (of 16)
    const int bk  = tid >> 4;          // 0..15 : B tile k-row
    const int bc4 = (tid & 15) * 4;    // 0..60 : B tile col

    float acc[4][4] = {};

    for (int k0 = 0; k0 < K; k0 += 16) {
        float4 av = *(const float4*)(A + (size_t)(m0 + ar) * K + k0 + ac4);
        float4 bv = *(const float4*)(W + (size_t)(k0 + bk) * N + n0 + bc4);
        __syncthreads();   // previous-iteration LDS reads complete
        As[(ac4 + 0) * 64 + ar] = av.x;
        As[(ac4 + 1) * 64 + ar] = av.y;
        As[(ac4 + 2) * 64 + ar] = av.z;
        As[(ac4 + 3) * 64 + ar] = av.w;
        *(float4*)&Bs[bk * 64 + bc4] = bv;
        __syncthreads();
        #pragma unroll
        for (int kk = 0; kk < 16; ++kk) {
            float4 a4 = *(const float4*)&As[kk * 64 + ty * 4];
            float4 b4 = *(const float4*)&Bs[kk * 64 + tx * 4];
            float aa[4] = {a4.x, a4.y, a4.z, a4.w};
            float bb[4] = {b4.x, b4.y, b4.z, b4.w};
            #pragma unroll
            for (int i = 0; i < 4; ++i)
                #pragma unroll
                for (int j = 0; j < 4; ++j)
                    acc[i][j] = fmaf(aa[i], bb[j], acc[i][j]);
        }
    }

    float4 bb4 = *(const float4*)(bias + n0 + tx * 4);
    float bvec[4] = {bb4.x, bb4.y, bb4.z, bb4.w};

    if (ep == 0) {
        const int h = blockIdx.x;   // N==768, grid.x==12
        #pragma unroll
        for (int i = 0; i < 4; ++i) {
            int m = m0 + ty * 4 + i;
            int b = m >> 11, t = m & (TT - 1);
            float4 o;
            o.x = acc[i][0] + bvec[0];
            o.y = acc[i][1] + bvec[1];
            o.z = acc[i][2] + bvec[2];
            o.w = acc[i][3] + bvec[3];
            *(float4*)(out + ((size_t)(b * TH + h) * TT + t) * TDH + tx * 4) = o;
        }
    } else if (ep == 1) {
        #pragma unroll
        for (int i = 0; i < 4; ++i) {
            int m = m0 + ty * 4 + i;
            float4 r4 = *(const float4*)(resid + (size_t)m * N + n0 + tx * 4);
            float4 o;
            o.x = acc[i][0] + bvec[0] + r4.x;
            o.y = acc[i][1] + bvec[1] + r4.y;
            o.z = acc[i][2] + bvec[2] + r4.z;
            o.w = acc[i][3] + bvec[3] + r4.w;
            *(float4*)(out + (size_t)m * N + n0 + tx * 4) = o;
        }
    } else {
        #pragma unroll
        for (int i = 0; i < 4; ++i) {
            int m = m0 + ty * 4 + i;
            float4 o;
            o.x = gelu_tanh(acc[i][0] + bvec[0]);
            o.y = gelu_tanh(acc[i][1] + bvec[1]);
            o.z = gelu_tanh(acc[i][2] + bvec[2]);
            o.w = gelu_tanh(acc[i][3] + bvec[3]);
            *(float4*)(out + (size_t)m * N + n0 + tx * 4) = o;
        }
    }
}

// ---------------------------------------------------------------------------
// LayerNorm (ddof=1, EPS=1e-4): out[row] = s * (x - mean)/sqrt(var + eps) + b
// One block (256 threads) per row of 768. Safe to run in-place (in == out).
// ---------------------------------------------------------------------------
__global__ __launch_bounds__(256)
void ln_kernel(const float* __restrict__ in, const float* __restrict__ gs,
               const float* __restrict__ gb, float* __restrict__ out)
{
    const int row = blockIdx.x, tid = threadIdx.x;
    const float* r = in + (size_t)row * TC;
    float x0 = r[tid], x1 = r[tid + 256], x2 = r[tid + 512];
    float s = x0 + x1 + x2;
    float q = x0 * x0 + x1 * x1 + x2 * x2;
    #pragma unroll
    for (int off = 32; off > 0; off >>= 1) {
        s += __shfl_down(s, off);
        q += __shfl_down(q, off);
    }
    __shared__ float partial[8];
    __shared__ float stats[2];
    int wid = tid >> 6, lane = tid & 63;
    if (lane == 0) { partial[wid] = s; partial[wid + 4] = q; }
    __syncthreads();
    if (tid == 0) {
        float S = partial[0] + partial[1] + partial[2] + partial[3];
        float Q = partial[4] + partial[5] + partial[6] + partial[7];
        float mean = S * (1.0f / (float)TC);
        float var = (Q - (float)TC * mean * mean) * (1.0f / (float)(TC - 1));
        stats[0] = mean;
        stats[1] = rsqrtf(var + 1e-4f);
    }
    __syncthreads();
    float mean = stats[0], rstd = stats[1];
    float* w = out + (size_t)row * TC;
    w[tid]       = gs[tid]       * ((x0 - mean) * rstd) + gb[tid];
    w[tid + 256] = gs[tid + 256] * ((x1 - mean) * rstd) + gb[tid + 256];
    w[tid + 512] = gs[tid + 512] * ((x2 - mean) * rstd) + gb[tid + 512];
}

// ---------------------------------------------------------------------------
// Flash-style causal attention, fp32.
// Q/K/V in [B,H,T,64]; out ctx in [B,T,768] (heads merged).
// Block: 256 threads, one (bh, 64-row q-tile). LDS: Qs(d-major), K/P union, Vs.
// Per-thread: 4 rows (ty*4+i) x 4 cols (tx*4+j); row reductions via 16-lane shfl.
// ---------------------------------------------------------------------------
#define ATT_STRIDE 68   // padded leading dim, keeps 16B alignment + bank spread

__global__ __launch_bounds__(256)
void attn_kernel(const float* __restrict__ Q, const float* __restrict__ K,
                 const float* __restrict__ V, float* __restrict__ ctx)
{
    __shared__ float Qs[64 * ATT_STRIDE];   // Qs[d][r]  (d-major)
    __shared__ float KPs[64 * ATT_STRIDE];  // K: [d][c] then reused as P: [r][c]
    __shared__ float Vs[64 * ATT_STRIDE];   // Vs[j][d]

    const int tid = threadIdx.x, tx = tid & 15, ty = tid >> 4;
    const int bh = blockIdx.y;
    const int qi = blockIdx.x;
    const int qt = (qi & 1) ? (31 - (qi >> 1)) : (qi >> 1);   // balance causal work
    const float* Qb = Q + (size_t)bh * TT * TDH;
    const float* Kb = K + (size_t)bh * TT * TDH;
    const float* Vb = V + (size_t)bh * TT * TDH;

    // stage Q tile transposed: Qs[d][r] = Q[qt*64+r][d]
    #pragma unroll
    for (int t = 0; t < 4; ++t) {
        int flat4 = tid + t * 256;          // float4 index 0..1023
        int r = flat4 >> 4, d0 = (flat4 & 15) * 4;
        float4 v = *(const float4*)(Qb + (size_t)(qt * 64 + r) * TDH + d0);
        Qs[(d0 + 0) * ATT_STRIDE + r] = v.x;
        Qs[(d0 + 1) * ATT_STRIDE + r] = v.y;
        Qs[(d0 + 2) * ATT_STRIDE + r] = v.z;
        Qs[(d0 + 3) * ATT_STRIDE + r] = v.w;
    }

    float m_i[4], l_i[4], o[4][4];
    #pragma unroll
    for (int i = 0; i < 4; ++i) {
        m_i[i] = -1e30f;
        l_i[i] = 0.0f;
        #pragma unroll
        for (int j = 0; j < 4; ++j) o[i][j] = 0.0f;
    }
    __syncthreads();

    for (int kt = 0; kt <= qt; ++kt) {
        // stage K (transposed) and V (direct)
        #pragma unroll
        for (int t = 0; t < 4; ++t) {
            int flat4 = tid + t * 256;
            int r = flat4 >> 4, d0 = (flat4 & 15) * 4;
            float4 kv = *(const float4*)(Kb + (size_t)(kt * 64 + r) * TDH + d0);
            KPs[(d0 + 0) * ATT_STRIDE + r] = kv.x;
            KPs[(d0 + 1) * ATT_STRIDE + r] = kv.y;
            KPs[(d0 + 2) * ATT_STRIDE + r] = kv.z;
            KPs[(d0 + 3) * ATT_STRIDE + r] = kv.w;
            float4 vv = *(const float4*)(Vb + (size_t)(kt * 64 + r) * TDH + d0);
            *(float4*)&Vs[r * ATT_STRIDE + d0] = vv;
        }
        __syncthreads();

        // S[r][c] = sum_d Q[r][d] * K[c][d]
        float s[4][4] = {};
        #pragma unroll 8
        for (int d = 0; d < 64; ++d) {
            float4 qa = *(const float4*)&Qs[d * ATT_STRIDE + ty * 4];
            float4 kb = *(const float4*)&KPs[d * ATT_STRIDE + tx * 4];
            float aa[4] = {qa.x, qa.y, qa.z, qa.w};
            float bb[4] = {kb.x, kb.y, kb.z, kb.w};
            #pragma unroll
            for (int i = 0; i < 4; ++i)
                #pragma unroll
                for (int j = 0; j < 4; ++j)
                    s[i][j] = fmaf(aa[i], bb[j], s[i][j]);
        }
        __syncthreads();   // K reads done; region becomes P

        // online softmax update + write P
        const int rbase = qt * 64 + ty * 4;
        const int cbase = kt * 64 + tx * 4;
        #pragma unroll
        for (int i = 0; i < 4; ++i) {
            int rg = rbase + i;
            float mx = -1e30f;
            #pragma unroll
            for (int j = 0; j < 4; ++j) {
                float sv = s[i][j] * 0.125f;            // 1/sqrt(64)
                if (cbase + j > rg) sv = -1e30f;        // causal mask
                s[i][j] = sv;
                mx = fmaxf(mx, sv);
            }
            mx = fmaxf(mx, __shfl_xor(mx, 1));
            mx = fmaxf(mx, __shfl_xor(mx, 2));
            mx = fmaxf(mx, __shfl_xor(mx, 4));
            mx = fmaxf(mx, __shfl_xor(mx, 8));
            float nm = fmaxf(m_i[i], mx);
            float corr = __expf(m_i[i] - nm);
            m_i[i] = nm;
            float p0 = __expf(s[i][0] - nm);
            float p1 = __expf(s[i][1] - nm);
            float p2 = __expf(s[i][2] - nm);
            float p3 = __expf(s[i][3] - nm);
            float ps = p0 + p1 + p2 + p3;
            ps += __shfl_xor(ps, 1);
            ps += __shfl_xor(ps, 2);
            ps += __shfl_xor(ps, 4);
            ps += __shfl_xor(ps, 8);
            l_i[i] = l_i[i] * corr + ps;
            #pragma unroll
            for (int j = 0; j < 4; ++j) o[i][j] *= corr;
            *(float4*)&KPs[(ty * 4 + i) * ATT_STRIDE + tx * 4] = make_float4(p0, p1, p2, p3);
        }
        __syncthreads();   // P visible

        // O[r][d] += sum_j P[r][j] * V[j][d]
        #pragma unroll 4
        for (int j4 = 0; j4 < 16; ++j4) {
            float pa[4][4], vv[4][4];
            #pragma unroll
            for (int i = 0; i < 4; ++i) {
                float4 t = *(const float4*)&KPs[(ty * 4 + i) * ATT_STRIDE + j4 * 4];
                pa[i][0] = t.x; pa[i][1] = t.y; pa[i][2] = t.z; pa[i][3] = t.w;
            }
            #pragma unroll
            for (int n = 0; n < 4; ++n) {
                float4 t = *(const float4*)&Vs[(j4 * 4 + n) * ATT_STRIDE + tx * 4];
                vv[n][0] = t.x; vv[n][1] = t.y; vv[n][2] = t.z; vv[n][3] = t.w;
            }
            #pragma unroll
            for (int i = 0; i < 4; ++i)
                #pragma unroll
                for (int n = 0; n < 4; ++n)
                    #pragma unroll
                    for (int j = 0; j < 4; ++j)
                        o[i][j] = fmaf(pa[i][n], vv[n][j], o[i][j]);
        }
        __syncthreads();   // P/V reads done before next stage
    }

    // epilogue: ctx[b][t][h*64 + d] = o / l
    const int b = bh / TH, h = bh - b * TH;
    #pragma unroll
    for (int i = 0; i < 4; ++i) {
        float inv = 1.0f / l_i[i];
        int t = qt * 64 + ty * 4 + i;
        float4 o4 = make_float4(o[i][0] * inv, o[i][1] * inv, o[i][2] * inv, o[i][3] * inv);
        *(float4*)(ctx + ((size_t)b * TT + t) * TC + h * TDH + tx * 4) = o4;
    }
}

// ---------------------------------------------------------------------------
extern "C" void kernel_launch(void* const* d_in, const int* in_sizes, int n_in,
                              void* d_out, int out_size, void* d_ws, size_t ws_size,
                              hipStream_t stream)
{
    const float* x    = (const float*)d_in[0];
    const float* Wq   = (const float*)d_in[1];
    const float* bq   = (const float*)d_in[2];
    const float* Wk   = (const float*)d_in[3];
    const float* bk   = (const float*)d_in[4];
    const float* Wv   = (const float*)d_in[5];
    const float* bv   = (const float*)d_in[6];
    const float* Wo   = (const float*)d_in[7];
    const float* bo   = (const float*)d_in[8];
    const float* ln1s = (const float*)d_in[9];
    const float* ln1b = (const float*)d_in[10];
    const float* W1   = (const float*)d_in[11];
    const float* b1   = (const float*)d_in[12];
    const float* W2   = (const float*)d_in[13];
    const float* b2   = (const float*)d_in[14];
    const float* ln2s = (const float*)d_in[15];
    const float* ln2b = (const float*)d_in[16];
    float* out = (float*)d_out;
    float* ws  = (float*)d_ws;

    const size_t MC = (size_t)TM * TC;   // 3,145,728 floats
    // Workspace layout (aliasing is deliberate; single stream serializes):
    //   [0,MC)   q      -> later tmp1 (pre-LN1) -> later part of u
    //   [MC,2MC) k      -> later part of u
    //   [2MC,3MC) v     -> later part of u
    //   [3MC,4MC) ctx   -> later part of u
    //   [4MC,5MC) h
    //   u (4096x3072) occupies [0,4MC)
    // Total: 5*MC*4 bytes = 62.9 MB
    float* qb   = ws;
    float* kb   = ws + MC;
    float* vb   = ws + 2 * MC;
    float* ctx  = ws + 3 * MC;
    float* tmp1 = ws;            // aliases qb (dead after attention)
    float* ub   = ws;            // aliases [0,4MC) (dead after LN1 reads tmp1)
    float* hb   = ws + 4 * MC;

    dim3 blk(256);
    dim3 g768(TC / 64, TM / 64);   // (12, 64)
    dim3 gI(TI / 64, TM / 64);     // (48, 64)

    gemm_ep<<<g768, blk, 0, stream>>>(x, Wq, bq, nullptr, qb, TM, TC, TC, 0);
    gemm_ep<<<g768, blk, 0, stream>>>(x, Wk, bk, nullptr, kb, TM, TC, TC, 0);
    gemm_ep<<<g768, blk, 0, stream>>>(x, Wv, bv, nullptr, vb, TM, TC, TC, 0);
    attn_kernel<<<dim3(TT / 64, TB * TH), blk, 0, stream>>>(qb, kb, vb, ctx);
    gemm_ep<<<g768, blk, 0, stream>>>(ctx, Wo, bo, x, tmp1, TM, TC, TC, 1);
    ln_kernel<<<dim3(TM), blk, 0, stream>>>(tmp1, ln1s, ln1b, hb);
    gemm_ep<<<gI, blk, 0, stream>>>(hb, W1, b1, nullptr, ub, TM, TI, TC, 2);
    gemm_ep<<<g768, blk, 0, stream>>>(ub, W2, b2, hb, out, TM, TC, TI, 1);
    ln_kernel<<<dim3(TM), blk, 0, stream>>>(out, ln2s, ln2b, out);   // in-place LN
}

// Round 2
// 705.810 us; speedup vs baseline: 1.8526x; 1.8526x over previous
//
#include <hip/hip_runtime.h>
#include <math.h>

#define TB  2
#define TT  2048
#define TC  768
#define TH  12
#define TDH 64
#define TI  3072
#define TM  (TB*TT)   // 4096 rows

typedef __attribute__((ext_vector_type(8))) __bf16 bf16x8;
typedef __attribute__((ext_vector_type(4))) __bf16 bf16x4;
typedef __attribute__((ext_vector_type(4))) float  f32x4;

__device__ __forceinline__ float gelu_tanh(float x) {
    float x3 = x * x * x;
    return 0.5f * x * (1.0f + tanhf(0.7978845608028654f * (x + 0.044715f * x3)));
}

// async global->LDS, 16B per lane. ldsptr must be the WAVE-UNIFORM base;
// HW writes lane l's 16B to base + l*16.
__device__ __forceinline__ void gld_lds16(const void* g, void* l) {
    __builtin_amdgcn_global_load_lds(
        (const __attribute__((address_space(1))) unsigned int*)g,
        (__attribute__((address_space(3))) unsigned int*)l,
        16, 0, 0);
}

// ---------------------------------------------------------------------------
// bf16 MFMA GEMM, m97 structure: 128x128 tile, BK=32, 256 thr = 4 waves (2x2),
// each wave 64x64 via 4x4 grid of 16x16x32 MFMA. A[M,K] bf16, Bt[N,K] bf16.
// Epilogues:
//  ep0: QKV split-head: q/k/v[z][((b*H+h)*T+t)*64+d] = acc + bias_z[n]
//  ep1: outf[m*N+n] = acc + bias[n] + resid[m*N+n]          (fp32 out)
//  ep2: outb[m*N+n] = bf16(gelu(acc + bias[n]))             (bf16 out)
// ---------------------------------------------------------------------------
#define BM 128
#define BN 128
#define BK 32

__global__ __launch_bounds__(256)
void gemm_mfma(const __bf16* __restrict__ A, const __bf16* __restrict__ Bt,
               const float* __restrict__ b0, const float* __restrict__ b1,
               const float* __restrict__ b2, const float* __restrict__ resid,
               float* __restrict__ outf, __bf16* __restrict__ outb,
               int N, int K, size_t wt_stride, size_t out_stride, int ep)
{
    __shared__ __align__(16) __bf16 As[BM * BK];   // 8 KB, row-major [m][k]
    __shared__ __align__(16) __bf16 Bs[BN * BK];   // 8 KB, row-major [n][k]

    const int tid  = threadIdx.x;
    const int wave = tid >> 6, lane = tid & 63;
    const int wm = wave >> 1, wn = wave & 1;
    const int m0 = blockIdx.y * BM, n0 = blockIdx.x * BN;
    const int z  = blockIdx.z;

    const __bf16* Bz = Bt + (size_t)z * wt_stride;

    // staging: thread t stages 16B: LDS byte (issue*4096 + t*16)
    //   -> tile row = issue*64 + (t>>2), k-byte = (t&3)*16
    const size_t Kb = (size_t)K * 2;                 // row stride in bytes
    const char* Ag = (const char*)A + (size_t)m0 * Kb;
    const char* Bg = (const char*)Bz + (size_t)n0 * Kb;
    const int srow = tid >> 2;
    const int scol = (tid & 3) * 16;
    char* AsB = (char*)As;
    char* BsB = (char*)Bs;
    const int wbase = wave * 1024;                   // wave-uniform LDS base

    f32x4 acc[4][4];
    #pragma unroll
    for (int i = 0; i < 4; ++i)
        #pragma unroll
        for (int j = 0; j < 4; ++j)
            acc[i][j] = (f32x4){0.f, 0.f, 0.f, 0.f};

    const int arow = wm * 64 + (lane & 15);
    const int brow = wn * 64 + (lane & 15);
    const int koff = (lane >> 4) * 8;

    for (int k0b = 0; k0b < (int)Kb; k0b += BK * 2) {
        __syncthreads();   // previous iteration's LDS reads complete
        gld_lds16(Ag + (size_t)srow * Kb        + k0b + scol, AsB + wbase);
        gld_lds16(Ag + (size_t)(srow + 64) * Kb + k0b + scol, AsB + 4096 + wbase);
        gld_lds16(Bg + (size_t)srow * Kb        + k0b + scol, BsB + wbase);
        gld_lds16(Bg + (size_t)(srow + 64) * Kb + k0b + scol, BsB + 4096 + wbase);
        __syncthreads();   // staging visible (syncthreads drains vmcnt)

        bf16x8 af[4], bfr[4];
        #pragma unroll
        for (int ti = 0; ti < 4; ++ti)
            af[ti] = *(const bf16x8*)&As[(arow + ti * 16) * BK + koff];
        #pragma unroll
        for (int tj = 0; tj < 4; ++tj)
            bfr[tj] = *(const bf16x8*)&Bs[(brow + tj * 16) * BK + koff];
        #pragma unroll
        for (int ti = 0; ti < 4; ++ti)
            #pragma unroll
            for (int tj = 0; tj < 4; ++tj)
                acc[ti][tj] = __builtin_amdgcn_mfma_f32_16x16x32_bf16(
                    af[ti], bfr[tj], acc[ti][tj], 0, 0, 0);
    }

    // C/D layout: col = lane&15, row = (lane>>4)*4 + r   [m89/m91 verified]
    const int lrow = m0 + wm * 64 + ((lane >> 4) << 2);
    const int lcol = n0 + wn * 64 + (lane & 15);

    if (ep == 0) {
        const float* bias = (z == 0) ? b0 : (z == 1) ? b1 : b2;
        float* outz = outf + (size_t)z * out_stride;
        #pragma unroll
        for (int tj = 0; tj < 4; ++tj) {
            int n = lcol + tj * 16;
            float bj = bias[n];
            int h = n >> 6, d = n & 63;
            #pragma unroll
            for (int ti = 0; ti < 4; ++ti)
                #pragma unroll
                for (int r = 0; r < 4; ++r) {
                    int m = lrow + ti * 16 + r;
                    int b = m >> 11, t = m & (TT - 1);
                    outz[((size_t)(b * TH + h) * TT + t) * TDH + d] =
                        acc[ti][tj][r] + bj;
                }
        }
    } else if (ep == 1) {
        #pragma unroll
        for (int tj = 0; tj < 4; ++tj) {
            int n = lcol + tj * 16;
            float bj = b0[n];
            #pragma unroll
            for (int ti = 0; ti < 4; ++ti)
                #pragma unroll
                for (int r = 0; r < 4; ++r) {
                    int m = lrow + ti * 16 + r;
                    outf[(size_t)m * N + n] =
                        acc[ti][tj][r] + bj + resid[(size_t)m * N + n];
                }
        }
    } else {
        #pragma unroll
        for (int tj = 0; tj < 4; ++tj) {
            int n = lcol + tj * 16;
            float bj = b0[n];
            #pragma unroll
            for (int ti = 0; ti < 4; ++ti)
                #pragma unroll
                for (int r = 0; r < 4; ++r) {
                    int m = lrow + ti * 16 + r;
                    outb[(size_t)m * N + n] = (__bf16)gelu_tanh(acc[ti][tj][r] + bj);
                }
        }
    }
}

// ---------------------------------------------------------------------------
// fp32 -> bf16 elementwise (n multiple of 2048)
// ---------------------------------------------------------------------------
__global__ __launch_bounds__(256)
void cvt_bf16(const float* __restrict__ in, __bf16* __restrict__ out, int n)
{
    int i = (blockIdx.x * 256 + threadIdx.x) * 8;
    if (i >= n) return;
    float4 a = *(const float4*)(in + i);
    float4 b = *(const float4*)(in + i + 4);
    bf16x8 v;
    v[0] = (__bf16)a.x; v[1] = (__bf16)a.y; v[2] = (__bf16)a.z; v[3] = (__bf16)a.w;
    v[4] = (__bf16)b.x; v[5] = (__bf16)b.y; v[6] = (__bf16)b.z; v[7] = (__bf16)b.w;
    *(bf16x8*)(out + i) = v;
}

// ---------------------------------------------------------------------------
// W[K,N] fp32 -> Wt[N,K] bf16, 32x32 LDS tile transpose. 256 threads.
// ---------------------------------------------------------------------------
__global__ __launch_bounds__(256)
void cvt_w_t(const float* __restrict__ W, __bf16* __restrict__ Wt, int K, int N)
{
    __shared__ float tile[32][33];
    const int k0 = blockIdx.y * 32, n0 = blockIdx.x * 32;
    const int tx = threadIdx.x & 31, ty = threadIdx.x >> 5;   // ty 0..7
    #pragma unroll
    for (int i = 0; i < 32; i += 8)
        tile[ty + i][tx] = W[(size_t)(k0 + ty + i) * N + n0 + tx];
    __syncthreads();
    #pragma unroll
    for (int i = 0; i < 32; i += 8)
        Wt[(size_t)(n0 + ty + i) * K + k0 + tx] = (__bf16)tile[tx][ty + i];
}

// ---------------------------------------------------------------------------
// LayerNorm (ddof=1, EPS=1e-4). Optionally writes a bf16 copy.
// ---------------------------------------------------------------------------
__global__ __launch_bounds__(256)
void ln_kernel(const float* __restrict__ in, const float* __restrict__ gs,
               const float* __restrict__ gb, float* __restrict__ out,
               __bf16* __restrict__ out_bf)
{
    const int row = blockIdx.x, tid = threadIdx.x;
    const float* r = in + (size_t)row * TC;
    float x0 = r[tid], x1 = r[tid + 256], x2 = r[tid + 512];
    float s = x0 + x1 + x2;
    float q = x0 * x0 + x1 * x1 + x2 * x2;
    #pragma unroll
    for (int off = 32; off > 0; off >>= 1) {
        s += __shfl_down(s, off);
        q += __shfl_down(q, off);
    }
    __shared__ float partial[8];
    __shared__ float stats[2];
    int wid = tid >> 6, lane = tid & 63;
    if (lane == 0) { partial[wid] = s; partial[wid + 4] = q; }
    __syncthreads();
    if (tid == 0) {
        float S = partial[0] + partial[1] + partial[2] + partial[3];
        float Q = partial[4] + partial[5] + partial[6] + partial[7];
        float mean = S * (1.0f / (float)TC);
        float var = (Q - (float)TC * mean * mean) * (1.0f / (float)(TC - 1));
        stats[0] = mean;
        stats[1] = rsqrtf(var + 1e-4f);
    }
    __syncthreads();
    float mean = stats[0], rstd = stats[1];
    float* w = out + (size_t)row * TC;
    float y0 = gs[tid]       * ((x0 - mean) * rstd) + gb[tid];
    float y1 = gs[tid + 256] * ((x1 - mean) * rstd) + gb[tid + 256];
    float y2 = gs[tid + 512] * ((x2 - mean) * rstd) + gb[tid + 512];
    w[tid] = y0; w[tid + 256] = y1; w[tid + 512] = y2;
    if (out_bf) {
        __bf16* wb = out_bf + (size_t)row * TC;
        wb[tid] = (__bf16)y0; wb[tid + 256] = (__bf16)y1; wb[tid + 512] = (__bf16)y2;
    }
}

// ---------------------------------------------------------------------------
// Flash-style causal attention, fp32 compute, bf16 ctx output.
// ---------------------------------------------------------------------------
#define ATT_STRIDE 68

__global__ __launch_bounds__(256)
void attn_kernel(const float* __restrict__ Q, const float* __restrict__ K,
                 const float* __restrict__ V, __bf16* __restrict__ ctx)
{
    __shared__ float Qs[64 * ATT_STRIDE];
    __shared__ float KPs[64 * ATT_STRIDE];
    __shared__ float Vs[64 * ATT_STRIDE];

    const int tid = threadIdx.x, tx = tid & 15, ty = tid >> 4;
    const int bh = blockIdx.y;
    const int qi = blockIdx.x;
    const int qt = (qi & 1) ? (31 - (qi >> 1)) : (qi >> 1);
    const float* Qb = Q + (size_t)bh * TT * TDH;
    const float* Kb = K + (size_t)bh * TT * TDH;
    const float* Vb = V + (size_t)bh * TT * TDH;

    #pragma unroll
    for (int t = 0; t < 4; ++t) {
        int flat4 = tid + t * 256;
        int r = flat4 >> 4, d0 = (flat4 & 15) * 4;
        float4 v = *(const float4*)(Qb + (size_t)(qt * 64 + r) * TDH + d0);
        Qs[(d0 + 0) * ATT_STRIDE + r] = v.x;
        Qs[(d0 + 1) * ATT_STRIDE + r] = v.y;
        Qs[(d0 + 2) * ATT_STRIDE + r] = v.z;
        Qs[(d0 + 3) * ATT_STRIDE + r] = v.w;
    }

    float m_i[4], l_i[4], o[4][4];
    #pragma unroll
    for (int i = 0; i < 4; ++i) {
        m_i[i] = -1e30f;
        l_i[i] = 0.0f;
        #pragma unroll
        for (int j = 0; j < 4; ++j) o[i][j] = 0.0f;
    }
    __syncthreads();

    for (int kt = 0; kt <= qt; ++kt) {
        #pragma unroll
        for (int t = 0; t < 4; ++t) {
            int flat4 = tid + t * 256;
            int r = flat4 >> 4, d0 = (flat4 & 15) * 4;
            float4 kv = *(const float4*)(Kb + (size_t)(kt * 64 + r) * TDH + d0);
            KPs[(d0 + 0) * ATT_STRIDE + r] = kv.x;
            KPs[(d0 + 1) * ATT_STRIDE + r] = kv.y;
            KPs[(d0 + 2) * ATT_STRIDE + r] = kv.z;
            KPs[(d0 + 3) * ATT_STRIDE + r] = kv.w;
            float4 vv = *(const float4*)(Vb + (size_t)(kt * 64 + r) * TDH + d0);
            *(float4*)&Vs[r * ATT_STRIDE + d0] = vv;
        }
        __syncthreads();

        float s[4][4] = {};
        #pragma unroll 8
        for (int d = 0; d < 64; ++d) {
            float4 qa = *(const float4*)&Qs[d * ATT_STRIDE + ty * 4];
            float4 kb = *(const float4*)&KPs[d * ATT_STRIDE + tx * 4];
            float aa[4] = {qa.x, qa.y, qa.z, qa.w};
            float bb[4] = {kb.x, kb.y, kb.z, kb.w};
            #pragma unroll
            for (int i = 0; i < 4; ++i)
                #pragma unroll
                for (int j = 0; j < 4; ++j)
                    s[i][j] = fmaf(aa[i], bb[j], s[i][j]);
        }
        __syncthreads();

        const int rbase = qt * 64 + ty * 4;
        const int cbase = kt * 64 + tx * 4;
        #pragma unroll
        for (int i = 0; i < 4; ++i) {
            int rg = rbase + i;
            float mx = -1e30f;
            #pragma unroll
            for (int j = 0; j < 4; ++j) {
                float sv = s[i][j] * 0.125f;
                if (cbase + j > rg) sv = -1e30f;
                s[i][j] = sv;
                mx = fmaxf(mx, sv);
            }
            mx = fmaxf(mx, __shfl_xor(mx, 1));
            mx = fmaxf(mx, __shfl_xor(mx, 2));
            mx = fmaxf(mx, __shfl_xor(mx, 4));
            mx = fmaxf(mx, __shfl_xor(mx, 8));
            float nm = fmaxf(m_i[i], mx);
            float corr = __expf(m_i[i] - nm);
            m_i[i] = nm;
            float p0 = __expf(s[i][0] - nm);
            float p1 = __expf(s[i][1] - nm);
            float p2 = __expf(s[i][2] - nm);
            float p3 = __expf(s[i][3] - nm);
            float ps = p0 + p1 + p2 + p3;
            ps += __shfl_xor(ps, 1);
            ps += __shfl_xor(ps, 2);
            ps += __shfl_xor(ps, 4);
            ps += __shfl_xor(ps, 8);
            l_i[i] = l_i[i] * corr + ps;
            #pragma unroll
            for (int j = 0; j < 4; ++j) o[i][j] *= corr;
            *(float4*)&KPs[(ty * 4 + i) * ATT_STRIDE + tx * 4] = make_float4(p0, p1, p2, p3);
        }
        __syncthreads();

        #pragma unroll 4
        for (int j4 = 0; j4 < 16; ++j4) {
            float pa[4][4], vv[4][4];
            #pragma unroll
            for (int i = 0; i < 4; ++i) {
                float4 t = *(const float4*)&KPs[(ty * 4 + i) * ATT_STRIDE + j4 * 4];
                pa[i][0] = t.x; pa[i][1] = t.y; pa[i][2] = t.z; pa[i][3] = t.w;
            }
            #pragma unroll
            for (int n = 0; n < 4; ++n) {
                float4 t = *(const float4*)&Vs[(j4 * 4 + n) * ATT_STRIDE + tx * 4];
                vv[n][0] = t.x; vv[n][1] = t.y; vv[n][2] = t.z; vv[n][3] = t.w;
            }
            #pragma unroll
            for (int i = 0; i < 4; ++i)
                #pragma unroll
                for (int n = 0; n < 4; ++n)
                    #pragma unroll
                    for (int j = 0; j < 4; ++j)
                        o[i][j] = fmaf(pa[i][n], vv[n][j], o[i][j]);
        }
        __syncthreads();
    }

    const int b = bh / TH, h = bh - b * TH;
    #pragma unroll
    for (int i = 0; i < 4; ++i) {
        float inv = 1.0f / l_i[i];
        int t = qt * 64 + ty * 4 + i;
        bf16x4 o4;
        o4[0] = (__bf16)(o[i][0] * inv);
        o4[1] = (__bf16)(o[i][1] * inv);
        o4[2] = (__bf16)(o[i][2] * inv);
        o4[3] = (__bf16)(o[i][3] * inv);
        *(bf16x4*)(ctx + ((size_t)b * TT + t) * TC + h * TDH + tx * 4) = o4;
    }
}

// ---------------------------------------------------------------------------
extern "C" void kernel_launch(void* const* d_in, const int* in_sizes, int n_in,
                              void* d_out, int out_size, void* d_ws, size_t ws_size,
                              hipStream_t stream)
{
    const float* x    = (const float*)d_in[0];
    const float* Wq   = (const float*)d_in[1];
    const float* bq   = (const float*)d_in[2];
    const float* Wk   = (const float*)d_in[3];
    const float* bk   = (const float*)d_in[4];
    const float* Wv   = (const float*)d_in[5];
    const float* bv   = (const float*)d_in[6];
    const float* Wo   = (const float*)d_in[7];
    const float* bo   = (const float*)d_in[8];
    const float* ln1s = (const float*)d_in[9];
    const float* ln1b = (const float*)d_in[10];
    const float* W1   = (const float*)d_in[11];
    const float* b1   = (const float*)d_in[12];
    const float* W2   = (const float*)d_in[13];
    const float* b2   = (const float*)d_in[14];
    const float* ln2s = (const float*)d_in[15];
    const float* ln2b = (const float*)d_in[16];
    float* out = (float*)d_out;
    float* ws  = (float*)d_ws;

    const size_t MC = (size_t)TM * TC;        // 3,145,728
    const size_t WSZ = (size_t)TC * TC;       // 589,824
    const size_t W12 = (size_t)TC * TI;       // 2,359,296

    // fp32 region: qkv [3][B,H,T,64] = 3*MC floats. Aliases after attention:
    //   tmp1  = q region      (written by proj, read by LN1)
    //   u_bf  = q+k regions   (2*MC floats = exactly 4096x3072 bf16)
    //   h_f32 = v region
    float* qkv   = ws;
    float* tmp1  = ws;
    __bf16* u_bf = (__bf16*)ws;
    float* h_f32 = ws + 2 * MC;

    // bf16 arena after qkv
    __bf16* arena  = (__bf16*)(ws + 3 * MC);
    __bf16* x_bf   = arena;
    __bf16* ctx_bf = arena + MC;
    __bf16* h_bf   = arena + 2 * MC;
    __bf16* WqkvT  = arena + 3 * MC;
    __bf16* WoT    = WqkvT + 3 * WSZ;
    __bf16* W1T    = WoT + WSZ;
    __bf16* W2T    = W1T + W12;

    dim3 blk(256);

    // conversions
    cvt_bf16<<<dim3((int)(MC / 2048)), blk, 0, stream>>>(x, x_bf, (int)MC);
    cvt_w_t<<<dim3(TC / 32, TC / 32), blk, 0, stream>>>(Wq, WqkvT,           TC, TC);
    cvt_w_t<<<dim3(TC / 32, TC / 32), blk, 0, stream>>>(Wk, WqkvT + WSZ,     TC, TC);
    cvt_w_t<<<dim3(TC / 32, TC / 32), blk, 0, stream>>>(Wv, WqkvT + 2 * WSZ, TC, TC);
    cvt_w_t<<<dim3(TC / 32, TC / 32), blk, 0, stream>>>(Wo, WoT, TC, TC);
    cvt_w_t<<<dim3(TI / 32, TC / 32), blk, 0, stream>>>(W1, W1T, TC, TI);
    cvt_w_t<<<dim3(TC / 32, TI / 32), blk, 0, stream>>>(W2, W2T, TI, TC);

    // QKV: one dispatch, z selects weight/bias/output
    gemm_mfma<<<dim3(TC / BN, TM / BM, 3), blk, 0, stream>>>(
        x_bf, WqkvT, bq, bk, bv, nullptr, qkv, nullptr, TC, TC, WSZ, MC, 0);

    attn_kernel<<<dim3(TT / 64, TB * TH), blk, 0, stream>>>(
        qkv, qkv + MC, qkv + 2 * MC, ctx_bf);

    // out-proj + residual(x) -> tmp1
    gemm_mfma<<<dim3(TC / BN, TM / BM, 1), blk, 0, stream>>>(
        ctx_bf, WoT, bo, nullptr, nullptr, x, tmp1, nullptr, TC, TC, 0, 0, 1);

    ln_kernel<<<dim3(TM), blk, 0, stream>>>(tmp1, ln1s, ln1b, h_f32, h_bf);

    // MLP1 + gelu -> u_bf
    gemm_mfma<<<dim3(TI / BN, TM / BM, 1), blk, 0, stream>>>(
        h_bf, W1T, b1, nullptr, nullptr, nullptr, nullptr, u_bf, TI, TC, 0, 0, 2);

    // MLP2 + residual(h) -> out
    gemm_mfma<<<dim3(TC / BN, TM / BM, 1), blk, 0, stream>>>(
        u_bf, W2T, b2, nullptr, nullptr, h_f32, out, nullptr, TC, TI, 0, 0, 1);

    ln_kernel<<<dim3(TM), blk, 0, stream>>>(out, ln2s, ln2b, out, nullptr);
}

// Round 3
// 392.897 us; speedup vs baseline: 3.3280x; 1.7964x over previous
//
#include <hip/hip_runtime.h>
#include <math.h>

#define TB  2
#define TT  2048
#define TC  768
#define TH  12
#define TDH 64
#define TI  3072
#define TM  (TB*TT)   // 4096 rows

typedef __attribute__((ext_vector_type(8))) __bf16 bf16x8;
typedef __attribute__((ext_vector_type(4))) __bf16 bf16x4;
typedef __attribute__((ext_vector_type(4))) float  f32x4;

__device__ __forceinline__ float gelu_tanh(float x) {
    float x3 = x * x * x;
    return 0.5f * x * (1.0f + tanhf(0.7978845608028654f * (x + 0.044715f * x3)));
}

// async global->LDS, 16B per lane (wave-uniform LDS base, lane l -> base+l*16)
__device__ __forceinline__ void gld_lds16(const void* g, void* l) {
    __builtin_amdgcn_global_load_lds(
        (const __attribute__((address_space(1))) unsigned int*)g,
        (__attribute__((address_space(3))) unsigned int*)l,
        16, 0, 0);
}

// ---------------------------------------------------------------------------
// bf16 MFMA GEMM (m97 structure): 128x128 tile, BK=32, 4 waves, 4x4 MFMA/wave.
// A[M,K] bf16, Bt[N,K] bf16.
// ep0: QKV. z=0: Q bf16 [bh][t][64]; z=1: K bf16 [bh][t][64];
//      z=2: V TRANSPOSED bf16 [bh][64][T]  (packed 4x t per store)
// ep1: outf[m*N+n] = acc + bias + resid   (fp32)
// ep2: outb[m*N+n] = bf16(gelu(acc+bias))
// ---------------------------------------------------------------------------
#define BM 128
#define BN 128
#define BK 32

__global__ __launch_bounds__(256)
void gemm_mfma(const __bf16* __restrict__ A, const __bf16* __restrict__ Bt,
               const float* __restrict__ b0, const float* __restrict__ b1,
               const float* __restrict__ b2, const float* __restrict__ resid,
               float* __restrict__ outf, __bf16* __restrict__ outb,
               int N, int K, size_t wt_stride, size_t out_stride, int ep)
{
    __shared__ __align__(16) __bf16 As[BM * BK];
    __shared__ __align__(16) __bf16 Bs[BN * BK];

    const int tid  = threadIdx.x;
    const int wave = tid >> 6, lane = tid & 63;
    const int wm = wave >> 1, wn = wave & 1;
    const int m0 = blockIdx.y * BM, n0 = blockIdx.x * BN;
    const int z  = blockIdx.z;

    const __bf16* Bz = Bt + (size_t)z * wt_stride;

    const size_t Kb = (size_t)K * 2;
    const char* Ag = (const char*)A + (size_t)m0 * Kb;
    const char* Bg = (const char*)Bz + (size_t)n0 * Kb;
    const int srow = tid >> 2;
    const int scol = (tid & 3) * 16;
    char* AsB = (char*)As;
    char* BsB = (char*)Bs;
    const int wbase = wave * 1024;

    f32x4 acc[4][4];
    #pragma unroll
    for (int i = 0; i < 4; ++i)
        #pragma unroll
        for (int j = 0; j < 4; ++j)
            acc[i][j] = (f32x4){0.f, 0.f, 0.f, 0.f};

    const int arow = wm * 64 + (lane & 15);
    const int brow = wn * 64 + (lane & 15);
    const int koff = (lane >> 4) * 8;

    for (int k0b = 0; k0b < (int)Kb; k0b += BK * 2) {
        __syncthreads();
        gld_lds16(Ag + (size_t)srow * Kb        + k0b + scol, AsB + wbase);
        gld_lds16(Ag + (size_t)(srow + 64) * Kb + k0b + scol, AsB + 4096 + wbase);
        gld_lds16(Bg + (size_t)srow * Kb        + k0b + scol, BsB + wbase);
        gld_lds16(Bg + (size_t)(srow + 64) * Kb + k0b + scol, BsB + 4096 + wbase);
        __syncthreads();

        bf16x8 af[4], bfr[4];
        #pragma unroll
        for (int ti = 0; ti < 4; ++ti)
            af[ti] = *(const bf16x8*)&As[(arow + ti * 16) * BK + koff];
        #pragma unroll
        for (int tj = 0; tj < 4; ++tj)
            bfr[tj] = *(const bf16x8*)&Bs[(brow + tj * 16) * BK + koff];
        #pragma unroll
        for (int ti = 0; ti < 4; ++ti)
            #pragma unroll
            for (int tj = 0; tj < 4; ++tj)
                acc[ti][tj] = __builtin_amdgcn_mfma_f32_16x16x32_bf16(
                    af[ti], bfr[tj], acc[ti][tj], 0, 0, 0);
    }

    // C/D: col = lane&15, row = (lane>>4)*4 + r
    const int lrow = m0 + wm * 64 + ((lane >> 4) << 2);
    const int lcol = n0 + wn * 64 + (lane & 15);

    if (ep == 0) {
        const float* bias = (z == 0) ? b0 : (z == 1) ? b1 : b2;
        __bf16* outz = outb + (size_t)z * out_stride;
        if (z < 2) {
            #pragma unroll
            for (int tj = 0; tj < 4; ++tj) {
                int n = lcol + tj * 16;
                float bj = bias[n];
                int h = n >> 6, d = n & 63;
                #pragma unroll
                for (int ti = 0; ti < 4; ++ti)
                    #pragma unroll
                    for (int r = 0; r < 4; ++r) {
                        int m = lrow + ti * 16 + r;
                        int b = m >> 11, t = m & (TT - 1);
                        outz[((size_t)(b * TH + h) * TT + t) * TDH + d] =
                            (__bf16)(acc[ti][tj][r] + bj);
                    }
            }
        } else {
            // V transposed: [bh][64][T], pack 4 consecutive t
            #pragma unroll
            for (int tj = 0; tj < 4; ++tj) {
                int n = lcol + tj * 16;
                float bj = bias[n];
                int h = n >> 6, d = n & 63;
                #pragma unroll
                for (int ti = 0; ti < 4; ++ti) {
                    int m = lrow + ti * 16;
                    int b = m >> 11, t0 = m & (TT - 1);
                    bf16x4 pk;
                    #pragma unroll
                    for (int r = 0; r < 4; ++r)
                        pk[r] = (__bf16)(acc[ti][tj][r] + bj);
                    *(bf16x4*)(outz + ((size_t)(b * TH + h) * TDH + d) * TT + t0) = pk;
                }
            }
        }
    } else if (ep == 1) {
        #pragma unroll
        for (int tj = 0; tj < 4; ++tj) {
            int n = lcol + tj * 16;
            float bj = b0[n];
            #pragma unroll
            for (int ti = 0; ti < 4; ++ti)
                #pragma unroll
                for (int r = 0; r < 4; ++r) {
                    int m = lrow + ti * 16 + r;
                    outf[(size_t)m * N + n] =
                        acc[ti][tj][r] + bj + resid[(size_t)m * N + n];
                }
        }
    } else {
        #pragma unroll
        for (int tj = 0; tj < 4; ++tj) {
            int n = lcol + tj * 16;
            float bj = b0[n];
            #pragma unroll
            for (int ti = 0; ti < 4; ++ti)
                #pragma unroll
                for (int r = 0; r < 4; ++r) {
                    int m = lrow + ti * 16 + r;
                    outb[(size_t)m * N + n] = (__bf16)gelu_tanh(acc[ti][tj][r] + bj);
                }
        }
    }
}

// ---------------------------------------------------------------------------
__global__ __launch_bounds__(256)
void cvt_bf16(const float* __restrict__ in, __bf16* __restrict__ out, int n)
{
    int i = (blockIdx.x * 256 + threadIdx.x) * 8;
    if (i >= n) return;
    float4 a = *(const float4*)(in + i);
    float4 b = *(const float4*)(in + i + 4);
    bf16x8 v;
    v[0] = (__bf16)a.x; v[1] = (__bf16)a.y; v[2] = (__bf16)a.z; v[3] = (__bf16)a.w;
    v[4] = (__bf16)b.x; v[5] = (__bf16)b.y; v[6] = (__bf16)b.z; v[7] = (__bf16)b.w;
    *(bf16x8*)(out + i) = v;
}

// W[K,N] fp32 -> Wt[N,K] bf16
__global__ __launch_bounds__(256)
void cvt_w_t(const float* __restrict__ W, __bf16* __restrict__ Wt, int K, int N)
{
    __shared__ float tile[32][33];
    const int k0 = blockIdx.y * 32, n0 = blockIdx.x * 32;
    const int tx = threadIdx.x & 31, ty = threadIdx.x >> 5;
    #pragma unroll
    for (int i = 0; i < 32; i += 8)
        tile[ty + i][tx] = W[(size_t)(k0 + ty + i) * N + n0 + tx];
    __syncthreads();
    #pragma unroll
    for (int i = 0; i < 32; i += 8)
        Wt[(size_t)(n0 + ty + i) * K + k0 + tx] = (__bf16)tile[tx][ty + i];
}

// ---------------------------------------------------------------------------
// LayerNorm (ddof=1, EPS=1e-4), optional bf16 copy
// ---------------------------------------------------------------------------
__global__ __launch_bounds__(256)
void ln_kernel(const float* __restrict__ in, const float* __restrict__ gs,
               const float* __restrict__ gb, float* __restrict__ out,
               __bf16* __restrict__ out_bf)
{
    const int row = blockIdx.x, tid = threadIdx.x;
    const float* r = in + (size_t)row * TC;
    float x0 = r[tid], x1 = r[tid + 256], x2 = r[tid + 512];
    float s = x0 + x1 + x2;
    float q = x0 * x0 + x1 * x1 + x2 * x2;
    #pragma unroll
    for (int off = 32; off > 0; off >>= 1) {
        s += __shfl_down(s, off);
        q += __shfl_down(q, off);
    }
    __shared__ float partial[8];
    __shared__ float stats[2];
    int wid = tid >> 6, lane = tid & 63;
    if (lane == 0) { partial[wid] = s; partial[wid + 4] = q; }
    __syncthreads();
    if (tid == 0) {
        float S = partial[0] + partial[1] + partial[2] + partial[3];
        float Q = partial[4] + partial[5] + partial[6] + partial[7];
        float mean = S * (1.0f / (float)TC);
        float var = (Q - (float)TC * mean * mean) * (1.0f / (float)(TC - 1));
        stats[0] = mean;
        stats[1] = rsqrtf(var + 1e-4f);
    }
    __syncthreads();
    float mean = stats[0], rstd = stats[1];
    float* w = out + (size_t)row * TC;
    float y0 = gs[tid]       * ((x0 - mean) * rstd) + gb[tid];
    float y1 = gs[tid + 256] * ((x1 - mean) * rstd) + gb[tid + 256];
    float y2 = gs[tid + 512] * ((x2 - mean) * rstd) + gb[tid + 512];
    w[tid] = y0; w[tid + 256] = y1; w[tid + 512] = y2;
    if (out_bf) {
        __bf16* wb = out_bf + (size_t)row * TC;
        wb[tid] = (__bf16)y0; wb[tid + 256] = (__bf16)y1; wb[tid + 512] = (__bf16)y2;
    }
}

// ---------------------------------------------------------------------------
// MFMA flash attention.
// Q,K bf16 [bh][T][64]; Vt bf16 [bh][64][T]; ctx bf16 [B][T][768].
// Block 256 thr = 4 waves; Q-tile 64 rows, wave w owns q rows qt*64+16w..+15.
// S^T = K.Q^T  (C col = q -> per-lane scalar softmax state)
// O^T = V^T.P^T (C col = q, row = d)
// LDS pitch 72 (144B = 9x16B): all b128 accesses aligned, conflict-free.
// ---------------------------------------------------------------------------
#define AP 72

__global__ __launch_bounds__(256)
void attn_mfma(const __bf16* __restrict__ Q, const __bf16* __restrict__ K,
               const __bf16* __restrict__ Vt, __bf16* __restrict__ ctx)
{
    __shared__ __align__(16) __bf16 Ks[64 * AP];
    __shared__ __align__(16) __bf16 Vs[64 * AP];
    __shared__ __align__(16) __bf16 Ps[64 * AP];

    const int tid  = threadIdx.x;
    const int wave = tid >> 6, lane = tid & 63;
    const int c = lane & 15, g = lane >> 4;
    const int bh = blockIdx.y;
    const int qi = blockIdx.x;
    const int qt = (qi & 1) ? (31 - (qi >> 1)) : (qi >> 1);   // causal balance
    const int q_glob = qt * 64 + wave * 16 + c;

    const __bf16* Qb = Q  + (size_t)bh * TT * TDH;
    const __bf16* Kb = K  + (size_t)bh * TT * TDH;
    const __bf16* Vb = Vt + (size_t)bh * TDH * TT;

    // Q fragments in registers for the whole block (B-frag: B[d][q]=Q[q][d])
    bf16x8 qf0 = *(const bf16x8*)(Qb + (size_t)q_glob * TDH + g * 8);
    bf16x8 qf1 = *(const bf16x8*)(Qb + (size_t)q_glob * TDH + 32 + g * 8);

    const int srow = tid >> 3;        // 0..31
    const int sc   = (tid & 7) * 8;   // bf16 elems, 16B chunks

    float m_i = -1e30f, l_i = 0.0f;
    f32x4 acc[4];
    #pragma unroll
    for (int m2 = 0; m2 < 4; ++m2) acc[m2] = (f32x4){0.f, 0.f, 0.f, 0.f};

    for (int kt = 0; kt <= qt; ++kt) {
        bf16x8 kv0 = *(const bf16x8*)(Kb + (size_t)(kt * 64 + srow) * TDH + sc);
        bf16x8 kv1 = *(const bf16x8*)(Kb + (size_t)(kt * 64 + srow + 32) * TDH + sc);
        bf16x8 vv0 = *(const bf16x8*)(Vb + (size_t)srow * TT + kt * 64 + sc);
        bf16x8 vv1 = *(const bf16x8*)(Vb + (size_t)(srow + 32) * TT + kt * 64 + sc);
        __syncthreads();   // prev-iteration LDS reads complete
        *(bf16x8*)&Ks[srow * AP + sc]        = kv0;
        *(bf16x8*)&Ks[(srow + 32) * AP + sc] = kv1;
        *(bf16x8*)&Vs[srow * AP + sc]        = vv0;
        *(bf16x8*)&Vs[(srow + 32) * AP + sc] = vv1;
        __syncthreads();

        // S^T = K.Q^T : A-frag rows = kcol, B-frag = Q regs
        f32x4 st[4];
        #pragma unroll
        for (int g2 = 0; g2 < 4; ++g2) {
            bf16x8 af0 = *(const bf16x8*)&Ks[(16 * g2 + c) * AP + g * 8];
            bf16x8 af1 = *(const bf16x8*)&Ks[(16 * g2 + c) * AP + 32 + g * 8];
            f32x4 z = (f32x4){0.f, 0.f, 0.f, 0.f};
            z = __builtin_amdgcn_mfma_f32_16x16x32_bf16(af0, qf0, z, 0, 0, 0);
            z = __builtin_amdgcn_mfma_f32_16x16x32_bf16(af1, qf1, z, 0, 0, 0);
            st[g2] = z;
        }

        // online softmax: per-lane q = q_glob (col of S^T)
        float sv[4][4];
        float mx = -1e30f;
        if (kt == qt) {
            #pragma unroll
            for (int g2 = 0; g2 < 4; ++g2)
                #pragma unroll
                for (int r = 0; r < 4; ++r) {
                    int kcol = kt * 64 + 16 * g2 + 4 * g + r;
                    float v = (kcol > q_glob) ? -1e30f : st[g2][r] * 0.125f;
                    sv[g2][r] = v;
                    mx = fmaxf(mx, v);
                }
        } else {
            #pragma unroll
            for (int g2 = 0; g2 < 4; ++g2)
                #pragma unroll
                for (int r = 0; r < 4; ++r) {
                    float v = st[g2][r] * 0.125f;
                    sv[g2][r] = v;
                    mx = fmaxf(mx, v);
                }
        }
        mx = fmaxf(mx, __shfl_xor(mx, 16));
        mx = fmaxf(mx, __shfl_xor(mx, 32));
        float nm = fmaxf(m_i, mx);
        float corr = __expf(m_i - nm);
        float ps = 0.f;
        #pragma unroll
        for (int g2 = 0; g2 < 4; ++g2) {
            bf16x4 pk;
            #pragma unroll
            for (int r = 0; r < 4; ++r) {
                float p = __expf(sv[g2][r] - nm);
                ps += p;
                pk[r] = (__bf16)p;
            }
            *(bf16x4*)&Ps[(wave * 16 + c) * AP + 16 * g2 + 4 * g] = pk;
        }
        ps += __shfl_xor(ps, 16);
        ps += __shfl_xor(ps, 32);
        l_i = l_i * corr + ps;
        m_i = nm;
        #pragma unroll
        for (int m2 = 0; m2 < 4; ++m2) {
            acc[m2][0] *= corr; acc[m2][1] *= corr;
            acc[m2][2] *= corr; acc[m2][3] *= corr;
        }

        // O^T += V^T.P^T  (per-wave Ps rows; same-wave write->read, no barrier)
        bf16x8 pf0 = *(const bf16x8*)&Ps[(wave * 16 + c) * AP + g * 8];
        bf16x8 pf1 = *(const bf16x8*)&Ps[(wave * 16 + c) * AP + 32 + g * 8];
        #pragma unroll
        for (int m2 = 0; m2 < 4; ++m2) {
            bf16x8 vf0 = *(const bf16x8*)&Vs[(16 * m2 + c) * AP + g * 8];
            bf16x8 vf1 = *(const bf16x8*)&Vs[(16 * m2 + c) * AP + 32 + g * 8];
            acc[m2] = __builtin_amdgcn_mfma_f32_16x16x32_bf16(vf0, pf0, acc[m2], 0, 0, 0);
            acc[m2] = __builtin_amdgcn_mfma_f32_16x16x32_bf16(vf1, pf1, acc[m2], 0, 0, 0);
        }
    }

    // epilogue: O^T[d][q] -> ctx[b][t=q][h*64+d], d = 16*m2 + 4*g + r
    const int b = bh / TH, h = bh - b * TH;
    float inv = 1.0f / l_i;
    #pragma unroll
    for (int m2 = 0; m2 < 4; ++m2) {
        bf16x4 o;
        #pragma unroll
        for (int r = 0; r < 4; ++r)
            o[r] = (__bf16)(acc[m2][r] * inv);
        *(bf16x4*)(ctx + ((size_t)b * TT + q_glob) * TC + h * TDH + 16 * m2 + 4 * g) = o;
    }
}

// ---------------------------------------------------------------------------
extern "C" void kernel_launch(void* const* d_in, const int* in_sizes, int n_in,
                              void* d_out, int out_size, void* d_ws, size_t ws_size,
                              hipStream_t stream)
{
    const float* x    = (const float*)d_in[0];
    const float* Wq   = (const float*)d_in[1];
    const float* bq   = (const float*)d_in[2];
    const float* Wk   = (const float*)d_in[3];
    const float* bk   = (const float*)d_in[4];
    const float* Wv   = (const float*)d_in[5];
    const float* bv   = (const float*)d_in[6];
    const float* Wo   = (const float*)d_in[7];
    const float* bo   = (const float*)d_in[8];
    const float* ln1s = (const float*)d_in[9];
    const float* ln1b = (const float*)d_in[10];
    const float* W1   = (const float*)d_in[11];
    const float* b1   = (const float*)d_in[12];
    const float* W2   = (const float*)d_in[13];
    const float* b2   = (const float*)d_in[14];
    const float* ln2s = (const float*)d_in[15];
    const float* ln2b = (const float*)d_in[16];
    float* out = (float*)d_out;

    const size_t MC  = (size_t)TM * TC;       // 3,145,728 elems
    const size_t MCB = MC * 2;                // bytes of one bf16 [TM,TC] buffer
    const size_t WSZ = (size_t)TC * TC;
    const size_t W12 = (size_t)TC * TI;

    // Byte layout (58.2 MB total), aliasing over the serial stream:
    //  [0,3MCB)      qkv bf16 (q,k,vt)  -> later tmp1 fp32 [0,2MCB) -> u_bf [0,4MCB)
    //  [3MCB,4MCB)   x_bf               -> later tail of u_bf
    //  [4MCB,6MCB)   h_f32 (fp32 MC)
    //  [6MCB,7MCB)   ctx_bf -> later h_bf
    //  [7MCB,...)    bf16 weights
    char* W = (char*)d_ws;
    __bf16* qkvb  = (__bf16*)W;
    __bf16* x_bf  = (__bf16*)(W + 3 * MCB);
    float*  tmp1  = (float*)W;
    __bf16* u_bf  = (__bf16*)W;
    float*  h_f32 = (float*)(W + 4 * MCB);
    __bf16* ctxh  = (__bf16*)(W + 6 * MCB);   // ctx_bf, then h_bf
    __bf16* wts   = (__bf16*)(W + 7 * MCB);
    __bf16* WqkvT = wts;
    __bf16* WoT   = WqkvT + 3 * WSZ;
    __bf16* W1T   = WoT + WSZ;
    __bf16* W2T   = W1T + W12;

    dim3 blk(256);

    cvt_bf16<<<dim3((int)(MC / 2048)), blk, 0, stream>>>(x, x_bf, (int)MC);
    cvt_w_t<<<dim3(TC / 32, TC / 32), blk, 0, stream>>>(Wq, WqkvT,           TC, TC);
    cvt_w_t<<<dim3(TC / 32, TC / 32), blk, 0, stream>>>(Wk, WqkvT + WSZ,     TC, TC);
    cvt_w_t<<<dim3(TC / 32, TC / 32), blk, 0, stream>>>(Wv, WqkvT + 2 * WSZ, TC, TC);
    cvt_w_t<<<dim3(TC / 32, TC / 32), blk, 0, stream>>>(Wo, WoT, TC, TC);
    cvt_w_t<<<dim3(TI / 32, TC / 32), blk, 0, stream>>>(W1, W1T, TC, TI);
    cvt_w_t<<<dim3(TC / 32, TI / 32), blk, 0, stream>>>(W2, W2T, TI, TC);

    // QKV (z: 0=Q, 1=K, 2=V^T), bf16 outputs
    gemm_mfma<<<dim3(TC / BN, TM / BM, 3), blk, 0, stream>>>(
        x_bf, WqkvT, bq, bk, bv, nullptr, nullptr, qkvb, TC, TC, WSZ, MC, 0);

    attn_mfma<<<dim3(TT / 64, TB * TH), blk, 0, stream>>>(
        qkvb, qkvb + MC, qkvb + 2 * MC, ctxh);

    // out-proj + residual(x) -> tmp1 (fp32)
    gemm_mfma<<<dim3(TC / BN, TM / BM, 1), blk, 0, stream>>>(
        ctxh, WoT, bo, nullptr, nullptr, x, tmp1, nullptr, TC, TC, 0, 0, 1);

    ln_kernel<<<dim3(TM), blk, 0, stream>>>(tmp1, ln1s, ln1b, h_f32, ctxh);

    // MLP1 + gelu -> u_bf
    gemm_mfma<<<dim3(TI / BN, TM / BM, 1), blk, 0, stream>>>(
        ctxh, W1T, b1, nullptr, nullptr, nullptr, nullptr, u_bf, TI, TC, 0, 0, 2);

    // MLP2 + residual(h) -> out
    gemm_mfma<<<dim3(TC / BN, TM / BM, 1), blk, 0, stream>>>(
        u_bf, W2T, b2, nullptr, nullptr, h_f32, out, nullptr, TC, TI, 0, 0, 1);

    ln_kernel<<<dim3(TM), blk, 0, stream>>>(out, ln2s, ln2b, out, nullptr);
}

// Round 4
// 322.560 us; speedup vs baseline: 4.0537x; 1.2181x over previous
//
#include <hip/hip_runtime.h>
#include <math.h>

#define TB  2
#define TT  2048
#define TC  768
#define TH  12
#define TDH 64
#define TI  3072
#define TM  (TB*TT)   // 4096 rows

typedef __attribute__((ext_vector_type(8))) __bf16 bf16x8;
typedef __attribute__((ext_vector_type(4))) __bf16 bf16x4;
typedef __attribute__((ext_vector_type(4))) float  f32x4;

__device__ __forceinline__ float gelu_tanh(float x) {
    float x3 = x * x * x;
    return 0.5f * x * (1.0f + tanhf(0.7978845608028654f * (x + 0.044715f * x3)));
}

// async global->LDS, 16B per lane (wave-uniform LDS base, lane l -> base+l*16)
__device__ __forceinline__ void gld_lds16(const void* g, void* l) {
    __builtin_amdgcn_global_load_lds(
        (const __attribute__((address_space(1))) unsigned int*)g,
        (__attribute__((address_space(3))) unsigned int*)l,
        16, 0, 0);
}

// ---------------------------------------------------------------------------
// bf16 MFMA GEMM, double-buffered LDS, XOR-swizzled chunks.
// Tile BM_ x BN_, BK=32, 4 waves arranged (BM_/WM_) x (BN_/WN_), wave tile
// WM_ x WN_ via (WM_/16)x(WN_/16) grid of 16x16x32 MFMA.
// LDS row = 32 bf16 = 4 chunks of 16B; chunk c of row r holds global chunk
// c ^ ((r>>2)&3)  -> b128 reads hit all 8 bank-slots exactly 2-way (free).
// K-loop: ONE barrier per iter; prefetch tile i+1 issued AFTER the barrier so
// the compiler's vmcnt(0)-before-barrier waits on loads issued a full
// iteration earlier (true overlap even at 1 block/CU).
// Epilogues: ep0 QKV (z=0 Q, z=1 K row-major [bh][t][64]; z=2 V^T [bh][64][T])
//            ep1 fp32 out = acc + bias + resid;  ep2 bf16 out = gelu(acc+bias)
// ---------------------------------------------------------------------------
#define BK 32

template<int BM_, int BN_, int WM_, int WN_>
__global__ __launch_bounds__(256)
void gemm_mfma(const __bf16* __restrict__ A, const __bf16* __restrict__ Bt,
               const float* __restrict__ b0, const float* __restrict__ b1,
               const float* __restrict__ b2, const float* __restrict__ resid,
               float* __restrict__ outf, __bf16* __restrict__ outb,
               int N, int K, size_t wt_stride, size_t out_stride, int ep)
{
    constexpr int WAVES_N = BN_ / WN_;
    constexpr int TMt = WM_ / 16, TNt = WN_ / 16;
    constexpr int AISS = BM_ / 64, BISS = BN_ / 64;
    constexpr int TILE = (BM_ + BN_) * BK;          // elems per buffer
    __shared__ __align__(16) __bf16 lds[2 * TILE];

    const int tid  = threadIdx.x;
    const int wave = tid >> 6, lane = tid & 63;
    const int wm = wave / WAVES_N, wn = wave % WAVES_N;
    const int m0 = blockIdx.y * BM_, n0 = blockIdx.x * BN_;
    const int z  = blockIdx.z;

    const __bf16* Bz = Bt + (size_t)z * wt_stride;
    const size_t Kb = (size_t)K * 2;
    const char* Ag = (const char*)A + (size_t)m0 * Kb;
    const char* Bg = (const char*)Bz + (size_t)n0 * Kb;
    const int srow = tid >> 2;
    const int scol = ((tid & 3) ^ ((tid >> 4) & 3)) * 16;   // swizzled src chunk
    const int wbase = wave * 1024;

    f32x4 acc[TMt][TNt];
    #pragma unroll
    for (int i = 0; i < TMt; ++i)
        #pragma unroll
        for (int j = 0; j < TNt; ++j)
            acc[i][j] = (f32x4){0.f, 0.f, 0.f, 0.f};

    const int arow = wm * WM_ + (lane & 15);
    const int brow = wn * WN_ + (lane & 15);
    const int koff = (((lane >> 4) ^ ((lane >> 2) & 3))) * 8;  // swizzled chunk

    const int nIter = K / BK;

    auto stage = [&](int buf, int k0b) {
        char* base = (char*)lds + (size_t)buf * TILE * 2;
        #pragma unroll
        for (int s = 0; s < AISS; ++s)
            gld_lds16(Ag + (size_t)(srow + 64 * s) * Kb + k0b + scol,
                      base + s * 4096 + wbase);
        char* bbase = base + BM_ * BK * 2;
        #pragma unroll
        for (int s = 0; s < BISS; ++s)
            gld_lds16(Bg + (size_t)(srow + 64 * s) * Kb + k0b + scol,
                      bbase + s * 4096 + wbase);
    };

    stage(0, 0);
    int buf = 0;
    for (int it = 0; it < nIter; ++it) {
        __syncthreads();   // drains vmcnt(0): tile-it loads (issued last iter) done
        if (it + 1 < nIter) stage(buf ^ 1, (it + 1) * (BK * 2));

        const __bf16* As = lds + (size_t)buf * TILE;
        const __bf16* Bs = As + BM_ * BK;
        bf16x8 af[TMt], bfr[TNt];
        #pragma unroll
        for (int ti = 0; ti < TMt; ++ti)
            af[ti] = *(const bf16x8*)&As[(arow + ti * 16) * BK + koff];
        #pragma unroll
        for (int tj = 0; tj < TNt; ++tj)
            bfr[tj] = *(const bf16x8*)&Bs[(brow + tj * 16) * BK + koff];
        #pragma unroll
        for (int ti = 0; ti < TMt; ++ti)
            #pragma unroll
            for (int tj = 0; tj < TNt; ++tj)
                acc[ti][tj] = __builtin_amdgcn_mfma_f32_16x16x32_bf16(
                    af[ti], bfr[tj], acc[ti][tj], 0, 0, 0);
        buf ^= 1;
    }

    // C/D: col = lane&15, row = (lane>>4)*4 + r
    const int lrow = m0 + wm * WM_ + ((lane >> 4) << 2);
    const int lcol = n0 + wn * WN_ + (lane & 15);

    if (ep == 0) {
        const float* bias = (z == 0) ? b0 : (z == 1) ? b1 : b2;
        __bf16* outz = outb + (size_t)z * out_stride;
        if (z < 2) {
            #pragma unroll
            for (int tj = 0; tj < TNt; ++tj) {
                int n = lcol + tj * 16;
                float bj = bias[n];
                int h = n >> 6, d = n & 63;
                #pragma unroll
                for (int ti = 0; ti < TMt; ++ti)
                    #pragma unroll
                    for (int r = 0; r < 4; ++r) {
                        int m = lrow + ti * 16 + r;
                        int b = m >> 11, t = m & (TT - 1);
                        outz[((size_t)(b * TH + h) * TT + t) * TDH + d] =
                            (__bf16)(acc[ti][tj][r] + bj);
                    }
            }
        } else {
            #pragma unroll
            for (int tj = 0; tj < TNt; ++tj) {
                int n = lcol + tj * 16;
                float bj = bias[n];
                int h = n >> 6, d = n & 63;
                #pragma unroll
                for (int ti = 0; ti < TMt; ++ti) {
                    int m = lrow + ti * 16;
                    int b = m >> 11, t0 = m & (TT - 1);
                    bf16x4 pk;
                    #pragma unroll
                    for (int r = 0; r < 4; ++r)
                        pk[r] = (__bf16)(acc[ti][tj][r] + bj);
                    *(bf16x4*)(outz + ((size_t)(b * TH + h) * TDH + d) * TT + t0) = pk;
                }
            }
        }
    } else if (ep == 1) {
        #pragma unroll
        for (int tj = 0; tj < TNt; ++tj) {
            int n = lcol + tj * 16;
            float bj = b0[n];
            #pragma unroll
            for (int ti = 0; ti < TMt; ++ti)
                #pragma unroll
                for (int r = 0; r < 4; ++r) {
                    int m = lrow + ti * 16 + r;
                    outf[(size_t)m * N + n] =
                        acc[ti][tj][r] + bj + resid[(size_t)m * N + n];
                }
        }
    } else {
        #pragma unroll
        for (int tj = 0; tj < TNt; ++tj) {
            int n = lcol + tj * 16;
            float bj = b0[n];
            #pragma unroll
            for (int ti = 0; ti < TMt; ++ti)
                #pragma unroll
                for (int r = 0; r < 4; ++r) {
                    int m = lrow + ti * 16 + r;
                    outb[(size_t)m * N + n] = (__bf16)gelu_tanh(acc[ti][tj][r] + bj);
                }
        }
    }
}

// ---------------------------------------------------------------------------
// Fused prep: x fp32->bf16 (blocks [0,1536)) + 6 weight transposes to bf16
// (blocks [1536, 1536+6912)): Wq,Wk,Wv,Wo (24x24 tiles each), W1 (96x24),
// W2 (24x96). One launch instead of 7.
// ---------------------------------------------------------------------------
__global__ __launch_bounds__(256)
void prep_kernel(const float* __restrict__ x,
                 const float* __restrict__ Wq, const float* __restrict__ Wk,
                 const float* __restrict__ Wv, const float* __restrict__ Wo,
                 const float* __restrict__ W1, const float* __restrict__ W2,
                 __bf16* __restrict__ x_bf, __bf16* __restrict__ WqkvT,
                 __bf16* __restrict__ WoT, __bf16* __restrict__ W1T,
                 __bf16* __restrict__ W2T)
{
    const size_t WSZ = (size_t)TC * TC;
    int bid = blockIdx.x;
    if (bid < 1536) {                        // x conversion: 1536*256*8 = MC
        int i = (bid * 256 + threadIdx.x) * 8;
        float4 a = *(const float4*)(x + i);
        float4 b = *(const float4*)(x + i + 4);
        bf16x8 v;
        v[0] = (__bf16)a.x; v[1] = (__bf16)a.y; v[2] = (__bf16)a.z; v[3] = (__bf16)a.w;
        v[4] = (__bf16)b.x; v[5] = (__bf16)b.y; v[6] = (__bf16)b.z; v[7] = (__bf16)b.w;
        *(bf16x8*)(x_bf + i) = v;
        return;
    }
    bid -= 1536;
    const float* src; __bf16* dst; int K, N, tloc;
    if (bid < 2304) {            // Wq/Wk/Wv/Wo: 576 tiles each
        int w = bid / 576; tloc = bid - w * 576;
        K = TC; N = TC;
        src = (w == 0) ? Wq : (w == 1) ? Wk : (w == 2) ? Wv : Wo;
        dst = (w < 3) ? (WqkvT + (size_t)w * WSZ) : WoT;
    } else if (bid < 4608) {     // W1 [768,3072]
        tloc = bid - 2304; K = TC; N = TI; src = W1; dst = W1T;
    } else {                     // W2 [3072,768]
        tloc = bid - 4608; K = TI; N = TC; src = W2; dst = W2T;
    }
    int tiles_x = N >> 5;
    int n0 = (tloc % tiles_x) * 32, k0 = (tloc / tiles_x) * 32;

    __shared__ float tile[32][33];
    const int tx = threadIdx.x & 31, ty = threadIdx.x >> 5;
    #pragma unroll
    for (int i = 0; i < 32; i += 8)
        tile[ty + i][tx] = src[(size_t)(k0 + ty + i) * N + n0 + tx];
    __syncthreads();
    #pragma unroll
    for (int i = 0; i < 32; i += 8)
        dst[(size_t)(n0 + ty + i) * K + k0 + tx] = (__bf16)tile[tx][ty + i];
}

// ---------------------------------------------------------------------------
// LayerNorm (ddof=1, EPS=1e-4), optional bf16 copy
// ---------------------------------------------------------------------------
__global__ __launch_bounds__(256)
void ln_kernel(const float* __restrict__ in, const float* __restrict__ gs,
               const float* __restrict__ gb, float* __restrict__ out,
               __bf16* __restrict__ out_bf)
{
    const int row = blockIdx.x, tid = threadIdx.x;
    const float* r = in + (size_t)row * TC;
    float x0 = r[tid], x1 = r[tid + 256], x2 = r[tid + 512];
    float s = x0 + x1 + x2;
    float q = x0 * x0 + x1 * x1 + x2 * x2;
    #pragma unroll
    for (int off = 32; off > 0; off >>= 1) {
        s += __shfl_down(s, off);
        q += __shfl_down(q, off);
    }
    __shared__ float partial[8];
    __shared__ float stats[2];
    int wid = tid >> 6, lane = tid & 63;
    if (lane == 0) { partial[wid] = s; partial[wid + 4] = q; }
    __syncthreads();
    if (tid == 0) {
        float S = partial[0] + partial[1] + partial[2] + partial[3];
        float Q = partial[4] + partial[5] + partial[6] + partial[7];
        float mean = S * (1.0f / (float)TC);
        float var = (Q - (float)TC * mean * mean) * (1.0f / (float)(TC - 1));
        stats[0] = mean;
        stats[1] = rsqrtf(var + 1e-4f);
    }
    __syncthreads();
    float mean = stats[0], rstd = stats[1];
    float* w = out + (size_t)row * TC;
    float y0 = gs[tid]       * ((x0 - mean) * rstd) + gb[tid];
    float y1 = gs[tid + 256] * ((x1 - mean) * rstd) + gb[tid + 256];
    float y2 = gs[tid + 512] * ((x2 - mean) * rstd) + gb[tid + 512];
    w[tid] = y0; w[tid + 256] = y1; w[tid + 512] = y2;
    if (out_bf) {
        __bf16* wb = out_bf + (size_t)row * TC;
        wb[tid] = (__bf16)y0; wb[tid + 256] = (__bf16)y1; wb[tid + 512] = (__bf16)y2;
    }
}

// ---------------------------------------------------------------------------
// MFMA flash attention (unchanged from round 3).
// ---------------------------------------------------------------------------
#define AP 72

__global__ __launch_bounds__(256)
void attn_mfma(const __bf16* __restrict__ Q, const __bf16* __restrict__ K,
               const __bf16* __restrict__ Vt, __bf16* __restrict__ ctx)
{
    __shared__ __align__(16) __bf16 Ks[64 * AP];
    __shared__ __align__(16) __bf16 Vs[64 * AP];
    __shared__ __align__(16) __bf16 Ps[64 * AP];

    const int tid  = threadIdx.x;
    const int wave = tid >> 6, lane = tid & 63;
    const int c = lane & 15, g = lane >> 4;
    const int bh = blockIdx.y;
    const int qi = blockIdx.x;
    const int qt = (qi & 1) ? (31 - (qi >> 1)) : (qi >> 1);
    const int q_glob = qt * 64 + wave * 16 + c;

    const __bf16* Qb = Q  + (size_t)bh * TT * TDH;
    const __bf16* Kb = K  + (size_t)bh * TT * TDH;
    const __bf16* Vb = Vt + (size_t)bh * TDH * TT;

    bf16x8 qf0 = *(const bf16x8*)(Qb + (size_t)q_glob * TDH + g * 8);
    bf16x8 qf1 = *(const bf16x8*)(Qb + (size_t)q_glob * TDH + 32 + g * 8);

    const int srow = tid >> 3;
    const int sc   = (tid & 7) * 8;

    float m_i = -1e30f, l_i = 0.0f;
    f32x4 acc[4];
    #pragma unroll
    for (int m2 = 0; m2 < 4; ++m2) acc[m2] = (f32x4){0.f, 0.f, 0.f, 0.f};

    for (int kt = 0; kt <= qt; ++kt) {
        bf16x8 kv0 = *(const bf16x8*)(Kb + (size_t)(kt * 64 + srow) * TDH + sc);
        bf16x8 kv1 = *(const bf16x8*)(Kb + (size_t)(kt * 64 + srow + 32) * TDH + sc);
        bf16x8 vv0 = *(const bf16x8*)(Vb + (size_t)srow * TT + kt * 64 + sc);
        bf16x8 vv1 = *(const bf16x8*)(Vb + (size_t)(srow + 32) * TT + kt * 64 + sc);
        __syncthreads();
        *(bf16x8*)&Ks[srow * AP + sc]        = kv0;
        *(bf16x8*)&Ks[(srow + 32) * AP + sc] = kv1;
        *(bf16x8*)&Vs[srow * AP + sc]        = vv0;
        *(bf16x8*)&Vs[(srow + 32) * AP + sc] = vv1;
        __syncthreads();

        f32x4 st[4];
        #pragma unroll
        for (int g2 = 0; g2 < 4; ++g2) {
            bf16x8 af0 = *(const bf16x8*)&Ks[(16 * g2 + c) * AP + g * 8];
            bf16x8 af1 = *(const bf16x8*)&Ks[(16 * g2 + c) * AP + 32 + g * 8];
            f32x4 z = (f32x4){0.f, 0.f, 0.f, 0.f};
            z = __builtin_amdgcn_mfma_f32_16x16x32_bf16(af0, qf0, z, 0, 0, 0);
            z = __builtin_amdgcn_mfma_f32_16x16x32_bf16(af1, qf1, z, 0, 0, 0);
            st[g2] = z;
        }

        float sv[4][4];
        float mx = -1e30f;
        if (kt == qt) {
            #pragma unroll
            for (int g2 = 0; g2 < 4; ++g2)
                #pragma unroll
                for (int r = 0; r < 4; ++r) {
                    int kcol = kt * 64 + 16 * g2 + 4 * g + r;
                    float v = (kcol > q_glob) ? -1e30f : st[g2][r] * 0.125f;
                    sv[g2][r] = v;
                    mx = fmaxf(mx, v);
                }
        } else {
            #pragma unroll
            for (int g2 = 0; g2 < 4; ++g2)
                #pragma unroll
                for (int r = 0; r < 4; ++r) {
                    float v = st[g2][r] * 0.125f;
                    sv[g2][r] = v;
                    mx = fmaxf(mx, v);
                }
        }
        mx = fmaxf(mx, __shfl_xor(mx, 16));
        mx = fmaxf(mx, __shfl_xor(mx, 32));
        float nm = fmaxf(m_i, mx);
        float corr = __expf(m_i - nm);
        float ps = 0.f;
        #pragma unroll
        for (int g2 = 0; g2 < 4; ++g2) {
            bf16x4 pk;
            #pragma unroll
            for (int r = 0; r < 4; ++r) {
                float p = __expf(sv[g2][r] - nm);
                ps += p;
                pk[r] = (__bf16)p;
            }
            *(bf16x4*)&Ps[(wave * 16 + c) * AP + 16 * g2 + 4 * g] = pk;
        }
        ps += __shfl_xor(ps, 16);
        ps += __shfl_xor(ps, 32);
        l_i = l_i * corr + ps;
        m_i = nm;
        #pragma unroll
        for (int m2 = 0; m2 < 4; ++m2) {
            acc[m2][0] *= corr; acc[m2][1] *= corr;
            acc[m2][2] *= corr; acc[m2][3] *= corr;
        }

        bf16x8 pf0 = *(const bf16x8*)&Ps[(wave * 16 + c) * AP + g * 8];
        bf16x8 pf1 = *(const bf16x8*)&Ps[(wave * 16 + c) * AP + 32 + g * 8];
        #pragma unroll
        for (int m2 = 0; m2 < 4; ++m2) {
            bf16x8 vf0 = *(const bf16x8*)&Vs[(16 * m2 + c) * AP + g * 8];
            bf16x8 vf1 = *(const bf16x8*)&Vs[(16 * m2 + c) * AP + 32 + g * 8];
            acc[m2] = __builtin_amdgcn_mfma_f32_16x16x32_bf16(vf0, pf0, acc[m2], 0, 0, 0);
            acc[m2] = __builtin_amdgcn_mfma_f32_16x16x32_bf16(vf1, pf1, acc[m2], 0, 0, 0);
        }
    }

    const int b = bh / TH, h = bh - b * TH;
    float inv = 1.0f / l_i;
    #pragma unroll
    for (int m2 = 0; m2 < 4; ++m2) {
        bf16x4 o;
        #pragma unroll
        for (int r = 0; r < 4; ++r)
            o[r] = (__bf16)(acc[m2][r] * inv);
        *(bf16x4*)(ctx + ((size_t)b * TT + q_glob) * TC + h * TDH + 16 * m2 + 4 * g) = o;
    }
}

// ---------------------------------------------------------------------------
extern "C" void kernel_launch(void* const* d_in, const int* in_sizes, int n_in,
                              void* d_out, int out_size, void* d_ws, size_t ws_size,
                              hipStream_t stream)
{
    const float* x    = (const float*)d_in[0];
    const float* Wq   = (const float*)d_in[1];
    const float* bq   = (const float*)d_in[2];
    const float* Wk   = (const float*)d_in[3];
    const float* bk   = (const float*)d_in[4];
    const float* Wv   = (const float*)d_in[5];
    const float* bv   = (const float*)d_in[6];
    const float* Wo   = (const float*)d_in[7];
    const float* bo   = (const float*)d_in[8];
    const float* ln1s = (const float*)d_in[9];
    const float* ln1b = (const float*)d_in[10];
    const float* W1   = (const float*)d_in[11];
    const float* b1   = (const float*)d_in[12];
    const float* W2   = (const float*)d_in[13];
    const float* b2   = (const float*)d_in[14];
    const float* ln2s = (const float*)d_in[15];
    const float* ln2b = (const float*)d_in[16];
    float* out = (float*)d_out;

    const size_t MC  = (size_t)TM * TC;       // 3,145,728 elems
    const size_t MCB = MC * 2;                // bytes of one bf16 [TM,TC]
    const size_t WSZ = (size_t)TC * TC;
    const size_t W12 = (size_t)TC * TI;

    // Byte layout (58.2 MB), aliasing over the serial stream:
    //  [0,3MCB)      qkv bf16 (q,k,vt)  -> later tmp1 fp32 -> u_bf
    //  [3MCB,4MCB)   x_bf               -> later tail of u_bf
    //  [4MCB,6MCB)   h_f32 (fp32)
    //  [6MCB,7MCB)   ctx_bf -> later h_bf
    //  [7MCB,...)    bf16 weights
    char* W = (char*)d_ws;
    __bf16* qkvb  = (__bf16*)W;
    __bf16* x_bf  = (__bf16*)(W + 3 * MCB);
    float*  tmp1  = (float*)W;
    __bf16* u_bf  = (__bf16*)W;
    float*  h_f32 = (float*)(W + 4 * MCB);
    __bf16* ctxh  = (__bf16*)(W + 6 * MCB);
    __bf16* wts   = (__bf16*)(W + 7 * MCB);
    __bf16* WqkvT = wts;
    __bf16* WoT   = WqkvT + 3 * WSZ;
    __bf16* W1T   = WoT + WSZ;
    __bf16* W2T   = W1T + W12;

    dim3 blk(256);

    prep_kernel<<<dim3(1536 + 6912), blk, 0, stream>>>(
        x, Wq, Wk, Wv, Wo, W1, W2, x_bf, WqkvT, WoT, W1T, W2T);

    // QKV (z: 0=Q, 1=K, 2=V^T): 128x128 tiles, grid 6x32x3 = 576 blocks
    gemm_mfma<128, 128, 64, 64><<<dim3(TC / 128, TM / 128, 3), blk, 0, stream>>>(
        x_bf, WqkvT, bq, bk, bv, nullptr, nullptr, qkvb, TC, TC, WSZ, MC, 0);

    attn_mfma<<<dim3(TT / 64, TB * TH), blk, 0, stream>>>(
        qkvb, qkvb + MC, qkvb + 2 * MC, ctxh);

    // out-proj + residual(x): 64x128 tiles, grid 6x64 = 384 blocks
    gemm_mfma<64, 128, 32, 64><<<dim3(TC / 128, TM / 64, 1), blk, 0, stream>>>(
        ctxh, WoT, bo, nullptr, nullptr, x, tmp1, nullptr, TC, TC, 0, 0, 1);

    ln_kernel<<<dim3(TM), blk, 0, stream>>>(tmp1, ln1s, ln1b, h_f32, ctxh);

    // MLP1 + gelu: 128x128 tiles, grid 24x32 = 768 blocks
    gemm_mfma<128, 128, 64, 64><<<dim3(TI / 128, TM / 128, 1), blk, 0, stream>>>(
        ctxh, W1T, b1, nullptr, nullptr, nullptr, nullptr, u_bf, TI, TC, 0, 0, 2);

    // MLP2 + residual(h): 64x128 tiles, grid 6x64 = 384 blocks
    gemm_mfma<64, 128, 32, 64><<<dim3(TC / 128, TM / 64, 1), blk, 0, stream>>>(
        u_bf, W2T, b2, nullptr, nullptr, h_f32, out, nullptr, TC, TI, 0, 0, 1);

    ln_kernel<<<dim3(TM), blk, 0, stream>>>(out, ln2s, ln2b, out, nullptr);
}